// Round 5
// baseline (226.562 us; speedup 1.0000x reference)
//
#include <hip/hip_runtime.h>
#include <hip/hip_fp16.h>

// GCN 2-layer. CSR-by-dst via 2-level LDS counting sort, register-blocked GEMM
// with fused dis-prescale writing PASS-BLOCKED fp16 g (P tables of [N][32],
// 3.2 MB each -> L2-resident per XCD), then per-pass node gather:
//   out_i = relu(dis_i * (g_i + sum_{src in N(i)} g_src) + b)
// Requires N < 65536 (edge packs into u32; csr indices are u16).

#define THREADS 256
#define EPB_HIST 4096
#define EPB_PART 4096   // 16 KB u32 stage, 2+ blocks/CU
#define MAXB 16384      // k_place stage capacity (bucket mean 8192)

__device__ inline int block_scan256(int v, int* wsum) {
    int lane = threadIdx.x & 63, w = threadIdx.x >> 6;
    int x = v;
    #pragma unroll
    for (int off = 1; off < 64; off <<= 1) {
        int y = __shfl_up(x, off);
        if (lane >= off) x += y;
    }
    if (lane == 63) wsum[w] = x;
    __syncthreads();
    int woff = 0;
    #pragma unroll
    for (int i = 0; i < 4; ++i) if (i < w) woff += wsum[i];
    return woff + x - v;
}

__global__ __launch_bounds__(256) void k_hist(const int* __restrict__ dst,
                                              int* __restrict__ bucketCnt, int E, int NB) {
    __shared__ int h[256];
    int t = threadIdx.x;
    h[t] = 0;
    __syncthreads();
    int base = blockIdx.x * EPB_HIST;
    int end = min(base + EPB_HIST, E);
    for (int e = base + t; e < end; e += 256) atomicAdd(&h[dst[e] >> 8], 1);
    __syncthreads();
    if (t < NB && h[t]) atomicAdd(&bucketCnt[t], h[t]);
}

__global__ __launch_bounds__(256) void k_bucket_scan(const int* __restrict__ bucketCnt,
                                                     int* __restrict__ bucketBase,
                                                     int* __restrict__ bucketCursor,
                                                     int NB, int E) {
    __shared__ int wsum[4];
    int t = threadIdx.x;
    int v = (t < NB) ? bucketCnt[t] : 0;
    int excl = block_scan256(v, wsum);
    if (t < NB) { bucketBase[t] = excl; bucketCursor[t] = excl; }
    if (t == 0) bucketBase[NB] = E;
}

__global__ __launch_bounds__(256) void k_partition(const int* __restrict__ src,
                                                   const int* __restrict__ dst,
                                                   int* __restrict__ bucketCursor,
                                                   unsigned int* __restrict__ bucketed, int E) {
    __shared__ int hist[256];
    __shared__ int localOff[256];
    __shared__ int runBase[256];
    __shared__ int wsum[4];
    __shared__ unsigned int stage[EPB_PART];
    int t = threadIdx.x;
    int base = blockIdx.x * EPB_PART;
    int nE = min(EPB_PART, E - base);
    hist[t] = 0;
    __syncthreads();
    for (int j = t; j < nE; j += 256) atomicAdd(&hist[dst[base + j] >> 8], 1);
    __syncthreads();
    int v = hist[t];
    int excl = block_scan256(v, wsum);
    localOff[t] = excl;
    if (v > 0) runBase[t] = atomicAdd(&bucketCursor[t], v);
    __syncthreads();
    hist[t] = excl;  // reuse as in-block cursor
    __syncthreads();
    for (int j = t; j < nE; j += 256) {
        int d = dst[base + j], s = src[base + j];
        int idx = atomicAdd(&hist[d >> 8], 1);
        stage[idx] = ((unsigned)d << 16) | (unsigned)s;
    }
    __syncthreads();
    for (int j = t; j < nE; j += 256) {
        unsigned u = stage[j];
        int b = u >> 24;  // == dst>>8 since dst<65536
        bucketed[runBase[b] + (j - localOff[b])] = u;
    }
}

__global__ __launch_bounds__(256) void k_place(const unsigned int* __restrict__ bucketed,
                                               const int* __restrict__ bucketBase,
                                               unsigned short* __restrict__ csr,
                                               int* __restrict__ row_ptr,
                                               float* __restrict__ dis, int N, int E) {
    __shared__ int nodeCnt[256];
    __shared__ int wsum[4];
    __shared__ unsigned short outS[MAXB];
    int b = blockIdx.x, t = threadIdx.x;
    int base = bucketBase[b];
    int cnt = bucketBase[b + 1] - base;
    nodeCnt[t] = 0;
    __syncthreads();
    for (int j = t; j < cnt; j += 256)
        atomicAdd(&nodeCnt[(bucketed[base + j] >> 16) & 255], 1);
    __syncthreads();
    int v = nodeCnt[t];
    int excl = block_scan256(v, wsum);
    int node = b * 256 + t;
    if (node < N) {
        row_ptr[node] = base + excl;
        dis[node] = rsqrtf(1.0f + (float)v);
        if (node == N - 1) row_ptr[N] = E;
    }
    __syncthreads();
    nodeCnt[t] = excl;  // reuse as cursor
    __syncthreads();
    for (int j = t; j < cnt; j += 256) {
        unsigned u = bucketed[base + j];
        int p = atomicAdd(&nodeCnt[(u >> 16) & 255], 1);
        if (p < MAXB) outS[p] = (unsigned short)(u & 0xFFFF);
    }
    __syncthreads();
    for (int j = t; j < cnt; j += 256) csr[base + j] = outS[j];
}

// Register-blocked GEMM writing pass-blocked g:
//   g[p][node][cw] = half( dis[node] * (x[node,:] @ W)[p*32+cw] )
template <int IN, int OUT, int CPT>
__global__ __launch_bounds__(256) void k_gemm(const float* __restrict__ x,
                                              const float* __restrict__ W,
                                              const float* __restrict__ dis,
                                              __half* __restrict__ g, int n) {
    constexpr int BN = 64;
    constexpr int XPAD = IN + 4;
    __shared__ float xs[BN * XPAD];
    __shared__ float Ws[IN * OUT];
    int t = threadIdx.x;
    for (int i = t; i < IN * OUT; i += 256) Ws[i] = W[i];
    int node0 = blockIdx.x * BN;
    for (int i = t; i < BN * IN; i += 256) {
        int r = i / IN, k = i % IN;
        int node = node0 + r;
        xs[r * XPAD + k] = (node < n) ? x[(size_t)node * IN + k] : 0.0f;
    }
    __syncthreads();
    constexpr int CG = OUT / CPT;
    int tc = t % CG, tn = t / CG;
    int c0 = tc * CPT, nb = tn * 4;
    float acc[4][CPT] = {};
    #pragma unroll 4
    for (int k = 0; k < IN; ++k) {
        float xv0 = xs[(nb + 0) * XPAD + k];
        float xv1 = xs[(nb + 1) * XPAD + k];
        float xv2 = xs[(nb + 2) * XPAD + k];
        float xv3 = xs[(nb + 3) * XPAD + k];
        #pragma unroll
        for (int c = 0; c < CPT; ++c) {
            float w = Ws[k * OUT + c0 + c];
            acc[0][c] += xv0 * w;
            acc[1][c] += xv1 * w;
            acc[2][c] += xv2 * w;
            acc[3][c] += xv3 * w;
        }
    }
    // pass-blocked epilogue: all CPT cols of this thread lie in one 32-col pass
    __half* gp = g + (size_t)(c0 >> 5) * ((size_t)n * 32);
    int cw = c0 & 31;
    #pragma unroll
    for (int i = 0; i < 4; ++i) {
        int node = node0 + nb + i;
        if (node < n) {
            float d = dis[node];
            #pragma unroll
            for (int c = 0; c < CPT; c += 2) {
                __half2 hv = __floats2half2_rn(d * acc[i][c], d * acc[i][c + 1]);
                *(__half2*)(&gp[(size_t)node * 32 + cw + c]) = hv;
            }
        }
    }
}

// One 32-col pass of the gather. 16-lane group per node (half2 per lane),
// shfl-broadcast indices, 8-deep MLP unroll. gt = [n][32] fp16 (3.2 MB).
__global__ __launch_bounds__(256) void k_gather_pass(const __half* __restrict__ gt,
                                                     const int* __restrict__ row_ptr,
                                                     const unsigned short* __restrict__ csr,
                                                     const float* __restrict__ dis,
                                                     const float* __restrict__ bias,
                                                     float* __restrict__ out,
                                                     int colbase, int outStride, int n) {
    int tid = threadIdx.x;
    int grp = tid >> 4, t = tid & 15;
    int lane = tid & 63;
    int gbase = lane & ~15;  // group base within wave
    int node = blockIdx.x * 16 + grp;
    if (node >= n) return;
    int beg = row_ptr[node], end = row_ptr[node + 1];
    float di = dis[node];
    const __half2* gp2 = (const __half2*)gt;  // row stride = 16 half2
    float2 sv = __half22float2(gp2[(size_t)node * 16 + t]);
    float a0 = sv.x, a1 = sv.y;
    for (int base = beg; base < end; base += 16) {
        int m = end - base; if (m > 16) m = 16;
        int idx = csr[base + (t < m ? t : 0)];
        int j = 0;
        for (; j + 8 <= m; j += 8) {
            int s0 = __shfl(idx, gbase + j + 0), s1 = __shfl(idx, gbase + j + 1);
            int s2 = __shfl(idx, gbase + j + 2), s3 = __shfl(idx, gbase + j + 3);
            int s4 = __shfl(idx, gbase + j + 4), s5 = __shfl(idx, gbase + j + 5);
            int s6 = __shfl(idx, gbase + j + 6), s7 = __shfl(idx, gbase + j + 7);
            float2 v0 = __half22float2(gp2[(size_t)s0 * 16 + t]);
            float2 v1 = __half22float2(gp2[(size_t)s1 * 16 + t]);
            float2 v2 = __half22float2(gp2[(size_t)s2 * 16 + t]);
            float2 v3 = __half22float2(gp2[(size_t)s3 * 16 + t]);
            float2 v4 = __half22float2(gp2[(size_t)s4 * 16 + t]);
            float2 v5 = __half22float2(gp2[(size_t)s5 * 16 + t]);
            float2 v6 = __half22float2(gp2[(size_t)s6 * 16 + t]);
            float2 v7 = __half22float2(gp2[(size_t)s7 * 16 + t]);
            a0 += ((v0.x + v1.x) + (v2.x + v3.x)) + ((v4.x + v5.x) + (v6.x + v7.x));
            a1 += ((v0.y + v1.y) + (v2.y + v3.y)) + ((v4.y + v5.y) + (v6.y + v7.y));
        }
        for (; j < m; ++j) {
            int s = __shfl(idx, gbase + j);
            float2 v = __half22float2(gp2[(size_t)s * 16 + t]);
            a0 += v.x; a1 += v.y;
        }
    }
    int c = colbase + t * 2;
    float o0 = fmaxf(di * a0 + bias[c], 0.0f);
    float o1 = fmaxf(di * a1 + bias[c + 1], 0.0f);
    *(float2*)(out + (size_t)node * outStride + c) = make_float2(o0, o1);
}

static inline size_t align_up(size_t v, size_t a) { return (v + a - 1) / a * a; }

extern "C" void kernel_launch(void* const* d_in, const int* in_sizes, int n_in,
                              void* d_out, int out_size, void* d_ws, size_t ws_size,
                              hipStream_t stream) {
    const float* x  = (const float*)d_in[0];
    const int*   ei = (const int*)d_in[1];
    const float* W1 = (const float*)d_in[2];
    const float* b1 = (const float*)d_in[3];
    const float* W2 = (const float*)d_in[4];
    const float* b2 = (const float*)d_in[5];
    float* out = (float*)d_out;

    const int N = in_sizes[0] / 64;   // 50000
    const int E = in_sizes[1] / 2;    // 1600000
    const int* src = ei;
    const int* dst = ei + E;
    const int NB = (N + 255) >> 8;    // 196 coarse buckets

    char* ws = (char*)d_ws;
    size_t off = 0;
    int* bucketCnt = (int*)(ws + off);      off = align_up(off + (size_t)NB * 4, 256);
    int* bucketBase = (int*)(ws + off);     off = align_up(off + (size_t)(NB + 1) * 4, 256);
    int* bucketCursor = (int*)(ws + off);   off = align_up(off + (size_t)NB * 4, 256);
    unsigned int* bucketed = (unsigned int*)(ws + off); off = align_up(off + (size_t)E * 4, 256);
    unsigned short* csr = (unsigned short*)(ws + off);  off = align_up(off + (size_t)E * 2, 256);
    int* row_ptr = (int*)(ws + off);        off = align_up(off + (size_t)(N + 1) * 4, 256);
    float* dis = (float*)(ws + off);        off = align_up(off + (size_t)N * 4, 256);
    __half* g = (__half*)(ws + off);        off = align_up(off + (size_t)N * 128 * 2, 256);
    float* y1 = (float*)(ws + off);         off = align_up(off + (size_t)N * 128 * 4, 256);
    (void)ws_size;

    const size_t passStride = (size_t)N * 32;  // halfs per pass table

    hipMemsetAsync(bucketCnt, 0, (size_t)NB * 4, stream);
    k_hist<<<(E + EPB_HIST - 1) / EPB_HIST, THREADS, 0, stream>>>(dst, bucketCnt, E, NB);
    k_bucket_scan<<<1, THREADS, 0, stream>>>(bucketCnt, bucketBase, bucketCursor, NB, E);
    k_partition<<<(E + EPB_PART - 1) / EPB_PART, THREADS, 0, stream>>>(src, dst, bucketCursor, bucketed, E);
    k_place<<<NB, THREADS, 0, stream>>>(bucketed, bucketBase, csr, row_ptr, dis, N, E);

    const int GGRID = (N + 15) / 16;

    // layer 1: g = half(dis * (x @ W1)) pass-blocked; y1 = relu(dis*(g_i+sum g_src)+b1)
    k_gemm<64, 128, 8><<<(N + 63) / 64, THREADS, 0, stream>>>(x, W1, dis, g, N);
    for (int p = 0; p < 4; ++p)
        k_gather_pass<<<GGRID, THREADS, 0, stream>>>(g + p * passStride, row_ptr, csr,
                                                     dis, b1, y1, p * 32, 128, N);

    // layer 2: g = half(dis * (y1 @ W2)) pass-blocked; out = relu(dis*(g_i+sum g_src)+b2)
    k_gemm<128, 64, 4><<<(N + 63) / 64, THREADS, 0, stream>>>(y1, W2, dis, g, N);
    for (int p = 0; p < 2; ++p)
        k_gather_pass<<<GGRID, THREADS, 0, stream>>>(g + p * passStride, row_ptr, csr,
                                                     dis, b2, out, p * 32, 64, N);
}

// Round 6
// 192.871 us; speedup vs baseline: 1.1747x; 1.1747x over previous
//
#include <hip/hip_runtime.h>
#include <hip/hip_fp16.h>

// GCN 2-layer, aggregate-first formulation:
//   layer1: agg1 = Â x          (gather over xh = half(dis*x), 64 cols, 6.4 MB)
//           y1   = relu(agg1 @ W1 + b1)
//   layer2: g2   = half(dis * (y1 @ W2))   (64 cols, 6.4 MB)
//           out  = relu(dis * (g2_i + sum g2_src) + b2)
// CSR-by-dst via 2-level LDS counting sort (no global memset, no fp atomics).
// Requires N < 65536 (edge packs into u32; csr indices are u16).

#define THREADS 256
#define EPB_HIST 4096
#define EPB_PART 4096   // 16 KB u32 stage
#define MAXB 16384      // k_place stage capacity (bucket mean 8192)

__device__ inline int block_scan256(int v, int* wsum) {
    int lane = threadIdx.x & 63, w = threadIdx.x >> 6;
    int x = v;
    #pragma unroll
    for (int off = 1; off < 64; off <<= 1) {
        int y = __shfl_up(x, off);
        if (lane >= off) x += y;
    }
    if (lane == 63) wsum[w] = x;
    __syncthreads();
    int woff = 0;
    #pragma unroll
    for (int i = 0; i < 4; ++i) if (i < w) woff += wsum[i];
    return woff + x - v;
}

// Per-block LDS histogram -> private row of histPart (no zeroed global needed).
__global__ __launch_bounds__(256) void k_hist(const int* __restrict__ dst,
                                              int* __restrict__ histPart, int E) {
    __shared__ int h[256];
    int t = threadIdx.x;
    h[t] = 0;
    __syncthreads();
    int base = blockIdx.x * EPB_HIST;
    int end = min(base + EPB_HIST, E);
    for (int e = base + t; e < end; e += 256) atomicAdd(&h[dst[e] >> 8], 1);
    __syncthreads();
    histPart[blockIdx.x * 256 + t] = h[t];
}

// Sum histPart rows, exclusive-scan -> bucketBase / bucketCursor.
__global__ __launch_bounds__(256) void k_bucket_scan(const int* __restrict__ histPart,
                                                     int nrows,
                                                     int* __restrict__ bucketBase,
                                                     int* __restrict__ bucketCursor,
                                                     int NB, int E) {
    __shared__ int wsum[4];
    int t = threadIdx.x;
    int s = 0, r = 0;
    for (; r + 4 <= nrows; r += 4) {
        int a = histPart[(r + 0) * 256 + t];
        int b = histPart[(r + 1) * 256 + t];
        int c = histPart[(r + 2) * 256 + t];
        int d = histPart[(r + 3) * 256 + t];
        s += (a + b) + (c + d);
    }
    for (; r < nrows; ++r) s += histPart[r * 256 + t];
    int excl = block_scan256(s, wsum);
    if (t < NB) { bucketBase[t] = excl; bucketCursor[t] = excl; }
    if (t == 0) bucketBase[NB] = E;
}

__global__ __launch_bounds__(256) void k_partition(const int* __restrict__ src,
                                                   const int* __restrict__ dst,
                                                   int* __restrict__ bucketCursor,
                                                   unsigned int* __restrict__ bucketed, int E) {
    __shared__ int hist[256];
    __shared__ int localOff[256];
    __shared__ int runBase[256];
    __shared__ int wsum[4];
    __shared__ unsigned int stage[EPB_PART];
    int t = threadIdx.x;
    int base = blockIdx.x * EPB_PART;
    int nE = min(EPB_PART, E - base);
    hist[t] = 0;
    __syncthreads();
    for (int j = t; j < nE; j += 256) atomicAdd(&hist[dst[base + j] >> 8], 1);
    __syncthreads();
    int v = hist[t];
    int excl = block_scan256(v, wsum);
    localOff[t] = excl;
    if (v > 0) runBase[t] = atomicAdd(&bucketCursor[t], v);
    __syncthreads();
    hist[t] = excl;  // reuse as in-block cursor
    __syncthreads();
    for (int j = t; j < nE; j += 256) {
        int d = dst[base + j], s = src[base + j];
        int idx = atomicAdd(&hist[d >> 8], 1);
        stage[idx] = ((unsigned)d << 16) | (unsigned)s;
    }
    __syncthreads();
    for (int j = t; j < nE; j += 256) {
        unsigned u = stage[j];
        int b = u >> 24;  // == dst>>8 since dst<65536
        bucketed[runBase[b] + (j - localOff[b])] = u;
    }
}

__global__ __launch_bounds__(256) void k_place(const unsigned int* __restrict__ bucketed,
                                               const int* __restrict__ bucketBase,
                                               unsigned short* __restrict__ csr,
                                               int* __restrict__ row_ptr,
                                               float* __restrict__ dis, int N, int E) {
    __shared__ int nodeCnt[256];
    __shared__ int wsum[4];
    __shared__ unsigned short outS[MAXB];
    int b = blockIdx.x, t = threadIdx.x;
    int base = bucketBase[b];
    int cnt = bucketBase[b + 1] - base;
    nodeCnt[t] = 0;
    __syncthreads();
    for (int j = t; j < cnt; j += 256)
        atomicAdd(&nodeCnt[(bucketed[base + j] >> 16) & 255], 1);
    __syncthreads();
    int v = nodeCnt[t];
    int excl = block_scan256(v, wsum);
    int node = b * 256 + t;
    if (node < N) {
        row_ptr[node] = base + excl;
        dis[node] = rsqrtf(1.0f + (float)v);
        if (node == N - 1) row_ptr[N] = E;
    }
    __syncthreads();
    nodeCnt[t] = excl;  // reuse as cursor
    __syncthreads();
    for (int j = t; j < cnt; j += 256) {
        unsigned u = bucketed[base + j];
        int p = atomicAdd(&nodeCnt[(u >> 16) & 255], 1);
        if (p < MAXB) outS[p] = (unsigned short)(u & 0xFFFF);
    }
    __syncthreads();
    for (int j = t; j < cnt; j += 256) csr[base + j] = outS[j];
}

// xh[i] = half(dis[node] * x[i])  (2 elems/thread)
__global__ __launch_bounds__(256) void k_cast(const float* __restrict__ x,
                                              const float* __restrict__ dis,
                                              __half* __restrict__ xh, int total) {
    int i = (blockIdx.x * 256 + threadIdx.x) * 2;
    if (i < total) {
        float d = dis[i >> 6];
        float2 v = *(const float2*)(x + i);
        *(__half2*)(xh + i) = __floats2half2_rn(d * v.x, d * v.y);
    }
}

// Wave-per-node gather over a 64-col fp16 table (dis-prescaled):
//   a = gt[node,lane] + sum_src gt[src,lane];  r = dis_node * a (+bias, relu)
template <bool RELU>
__global__ __launch_bounds__(256) void k_gather64(const __half* __restrict__ gt,
                                                  const int* __restrict__ row_ptr,
                                                  const unsigned short* __restrict__ csr,
                                                  const float* __restrict__ dis,
                                                  const float* __restrict__ bias,
                                                  float* __restrict__ out, int n) {
    int wave = threadIdx.x >> 6, lane = threadIdx.x & 63;
    int node = blockIdx.x * 4 + wave;
    if (node >= n) return;
    int beg = row_ptr[node], end = row_ptr[node + 1];
    float a = __half2float(gt[(size_t)node * 64 + lane]);
    for (int base = beg; base < end; base += 64) {
        int m = end - base; if (m > 64) m = 64;
        int idx = csr[base + (lane < m ? lane : 0)];
        int j = 0;
        for (; j + 16 <= m; j += 16) {
            int s0 = __shfl(idx, j + 0),  s1 = __shfl(idx, j + 1);
            int s2 = __shfl(idx, j + 2),  s3 = __shfl(idx, j + 3);
            int s4 = __shfl(idx, j + 4),  s5 = __shfl(idx, j + 5);
            int s6 = __shfl(idx, j + 6),  s7 = __shfl(idx, j + 7);
            int s8 = __shfl(idx, j + 8),  s9 = __shfl(idx, j + 9);
            int sa = __shfl(idx, j + 10), sb = __shfl(idx, j + 11);
            int sc = __shfl(idx, j + 12), sd = __shfl(idx, j + 13);
            int se = __shfl(idx, j + 14), sf = __shfl(idx, j + 15);
            __half v0 = gt[(size_t)s0 * 64 + lane], v1 = gt[(size_t)s1 * 64 + lane];
            __half v2 = gt[(size_t)s2 * 64 + lane], v3 = gt[(size_t)s3 * 64 + lane];
            __half v4 = gt[(size_t)s4 * 64 + lane], v5 = gt[(size_t)s5 * 64 + lane];
            __half v6 = gt[(size_t)s6 * 64 + lane], v7 = gt[(size_t)s7 * 64 + lane];
            __half v8 = gt[(size_t)s8 * 64 + lane], v9 = gt[(size_t)s9 * 64 + lane];
            __half va = gt[(size_t)sa * 64 + lane], vb = gt[(size_t)sb * 64 + lane];
            __half vc = gt[(size_t)sc * 64 + lane], vd = gt[(size_t)sd * 64 + lane];
            __half ve = gt[(size_t)se * 64 + lane], vf = gt[(size_t)sf * 64 + lane];
            float f0 = (__half2float(v0) + __half2float(v1)) + (__half2float(v2) + __half2float(v3));
            float f1 = (__half2float(v4) + __half2float(v5)) + (__half2float(v6) + __half2float(v7));
            float f2 = (__half2float(v8) + __half2float(v9)) + (__half2float(va) + __half2float(vb));
            float f3 = (__half2float(vc) + __half2float(vd)) + (__half2float(ve) + __half2float(vf));
            a += (f0 + f1) + (f2 + f3);
        }
        for (; j + 4 <= m; j += 4) {
            int s0 = __shfl(idx, j + 0), s1 = __shfl(idx, j + 1);
            int s2 = __shfl(idx, j + 2), s3 = __shfl(idx, j + 3);
            __half v0 = gt[(size_t)s0 * 64 + lane], v1 = gt[(size_t)s1 * 64 + lane];
            __half v2 = gt[(size_t)s2 * 64 + lane], v3 = gt[(size_t)s3 * 64 + lane];
            a += (__half2float(v0) + __half2float(v1)) + (__half2float(v2) + __half2float(v3));
        }
        for (; j < m; ++j) {
            int s = __shfl(idx, j);
            a += __half2float(gt[(size_t)s * 64 + lane]);
        }
    }
    float r = dis[node] * a;
    if constexpr (RELU) r = fmaxf(r + bias[lane], 0.0f);
    out[(size_t)node * 64 + lane] = r;
}

// Register-blocked GEMM, 64 nodes/block, thread = 4 nodes x CPT cols.
// MODE 0: outf = relu(acc + bias)   MODE 1: outh = half(dis * acc)
template <int IN, int OUT, int CPT, int MODE>
__global__ __launch_bounds__(256) void k_gemm(const float* __restrict__ x,
                                              const float* __restrict__ W,
                                              const float* __restrict__ dis,
                                              const float* __restrict__ bias,
                                              float* __restrict__ outf,
                                              __half* __restrict__ outh, int n) {
    constexpr int BN = 64;
    constexpr int XPAD = IN + 4;
    __shared__ float xs[BN * XPAD];
    __shared__ float Ws[IN * OUT];
    int t = threadIdx.x;
    for (int i = t; i < IN * OUT; i += 256) Ws[i] = W[i];
    int node0 = blockIdx.x * BN;
    for (int i = t; i < BN * IN; i += 256) {
        int r = i / IN, k = i % IN;
        int node = node0 + r;
        xs[r * XPAD + k] = (node < n) ? x[(size_t)node * IN + k] : 0.0f;
    }
    __syncthreads();
    constexpr int CG = OUT / CPT;
    int tc = t % CG, tn = t / CG;
    int c0 = tc * CPT, nb = tn * 4;
    float acc[4][CPT] = {};
    #pragma unroll 4
    for (int k = 0; k < IN; ++k) {
        float xv0 = xs[(nb + 0) * XPAD + k];
        float xv1 = xs[(nb + 1) * XPAD + k];
        float xv2 = xs[(nb + 2) * XPAD + k];
        float xv3 = xs[(nb + 3) * XPAD + k];
        #pragma unroll
        for (int c = 0; c < CPT; ++c) {
            float w = Ws[k * OUT + c0 + c];
            acc[0][c] += xv0 * w;
            acc[1][c] += xv1 * w;
            acc[2][c] += xv2 * w;
            acc[3][c] += xv3 * w;
        }
    }
    #pragma unroll
    for (int i = 0; i < 4; ++i) {
        int node = node0 + nb + i;
        if (node < n) {
            if constexpr (MODE == 0) {
                #pragma unroll
                for (int c = 0; c < CPT; ++c)
                    outf[(size_t)node * OUT + c0 + c] = fmaxf(acc[i][c] + bias[c0 + c], 0.0f);
            } else {
                float d = dis[node];
                #pragma unroll
                for (int c = 0; c < CPT; c += 2) {
                    __half2 hv = __floats2half2_rn(d * acc[i][c], d * acc[i][c + 1]);
                    *(__half2*)(&outh[(size_t)node * OUT + c0 + c]) = hv;
                }
            }
        }
    }
}

static inline size_t align_up(size_t v, size_t a) { return (v + a - 1) / a * a; }

extern "C" void kernel_launch(void* const* d_in, const int* in_sizes, int n_in,
                              void* d_out, int out_size, void* d_ws, size_t ws_size,
                              hipStream_t stream) {
    const float* x  = (const float*)d_in[0];
    const int*   ei = (const int*)d_in[1];
    const float* W1 = (const float*)d_in[2];
    const float* b1 = (const float*)d_in[3];
    const float* W2 = (const float*)d_in[4];
    const float* b2 = (const float*)d_in[5];
    float* out = (float*)d_out;

    const int N = in_sizes[0] / 64;   // 50000
    const int E = in_sizes[1] / 2;    // 1600000
    const int* src = ei;
    const int* dst = ei + E;
    const int NB = (N + 255) >> 8;    // 196 coarse buckets
    const int HBLK = (E + EPB_HIST - 1) / EPB_HIST;

    char* ws = (char*)d_ws;
    size_t off = 0;
    int* histPart = (int*)(ws + off);       off = align_up(off + (size_t)HBLK * 256 * 4, 256);
    int* bucketBase = (int*)(ws + off);     off = align_up(off + (size_t)(NB + 1) * 4, 256);
    int* bucketCursor = (int*)(ws + off);   off = align_up(off + (size_t)NB * 4, 256);
    unsigned int* bucketed = (unsigned int*)(ws + off); off = align_up(off + (size_t)E * 4, 256);
    unsigned short* csr = (unsigned short*)(ws + off);  off = align_up(off + (size_t)E * 2, 256);
    int* row_ptr = (int*)(ws + off);        off = align_up(off + (size_t)(N + 1) * 4, 256);
    float* dis = (float*)(ws + off);        off = align_up(off + (size_t)N * 4, 256);
    __half* xh = (__half*)(ws + off);       off = align_up(off + (size_t)N * 64 * 2, 256);
    float* agg1 = (float*)(ws + off);       off = align_up(off + (size_t)N * 64 * 4, 256);
    float* y1 = (float*)(ws + off);         off = align_up(off + (size_t)N * 128 * 4, 256);
    __half* g2 = (__half*)(ws + off);       off = align_up(off + (size_t)N * 64 * 2, 256);
    (void)ws_size;

    // CSR build
    k_hist<<<HBLK, THREADS, 0, stream>>>(dst, histPart, E);
    k_bucket_scan<<<1, THREADS, 0, stream>>>(histPart, HBLK, bucketBase, bucketCursor, NB, E);
    k_partition<<<(E + EPB_PART - 1) / EPB_PART, THREADS, 0, stream>>>(src, dst, bucketCursor, bucketed, E);
    k_place<<<NB, THREADS, 0, stream>>>(bucketed, bucketBase, csr, row_ptr, dis, N, E);

    // layer 1: aggregate-first
    k_cast<<<(N * 64 / 2 + THREADS - 1) / THREADS, THREADS, 0, stream>>>(x, dis, xh, N * 64);
    k_gather64<false><<<(N + 3) / 4, THREADS, 0, stream>>>(xh, row_ptr, csr, dis, b1, agg1, N);
    k_gemm<64, 128, 8, 0><<<(N + 63) / 64, THREADS, 0, stream>>>(agg1, W1, nullptr, b1, y1, nullptr, N);

    // layer 2: aggregate-last
    k_gemm<128, 64, 4, 1><<<(N + 63) / 64, THREADS, 0, stream>>>(y1, W2, dis, nullptr, nullptr, g2, N);
    k_gather64<true><<<(N + 3) / 4, THREADS, 0, stream>>>(g2, row_ptr, csr, dis, b2, out, N);
}

// Round 7
// 174.463 us; speedup vs baseline: 1.2986x; 1.1055x over previous
//
#include <hip/hip_runtime.h>
#include <hip/hip_fp16.h>

// GCN 2-layer, aggregate-first L1 / aggregate-last L2:
//   agg1 = Â x   (gather over xh = half(dis*x), 64-col, produced in k_place)
//   g2   = half(dis * (relu(agg1@W1+b1) @ W2))   (fused double-GEMM, y1 in LDS)
//   out  = relu(dis * (g2_i + sum g2_src) + b2)  (gather)
// CSR build: direct fixed-capacity bucket partition (no hist pass) + in-LDS
// per-bucket placement fused with the xh cast. N < 65536 (u16 csr indices).

#define THREADS 256
#define EPB 4096    // edges per partition block (16 KB LDS stage)
#define CAP 16384   // per-bucket capacity (mean 8163, ~90 sigma headroom)

__device__ inline int block_scan256(int v, int* wsum) {
    int lane = threadIdx.x & 63, w = threadIdx.x >> 6;
    int x = v;
    #pragma unroll
    for (int off = 1; off < 64; off <<= 1) {
        int y = __shfl_up(x, off);
        if (lane >= off) x += y;
    }
    if (lane == 63) wsum[w] = x;
    __syncthreads();
    int woff = 0;
    #pragma unroll
    for (int i = 0; i < 4; ++i) if (i < w) woff += wsum[i];
    return woff + x - v;
}

// Direct partition: group 4096 edges by coarse bucket (dst>>8) in LDS, reserve
// bucket space via one global atomicAdd per (block,bucket), write grouped runs.
__global__ __launch_bounds__(256) void k_partition(const int* __restrict__ src,
                                                   const int* __restrict__ dst,
                                                   int* __restrict__ bucketCnt,
                                                   unsigned int* __restrict__ bucketed, int E) {
    __shared__ int hist[256];
    __shared__ int localOff[256];
    __shared__ int runBase[256];
    __shared__ int wsum[4];
    __shared__ unsigned int stage[EPB];
    int t = threadIdx.x;
    int base = blockIdx.x * EPB;
    int nE = min(EPB, E - base);
    hist[t] = 0;
    __syncthreads();
    for (int j = t; j < nE; j += 256) atomicAdd(&hist[dst[base + j] >> 8], 1);
    __syncthreads();
    int v = hist[t];
    int excl = block_scan256(v, wsum);
    localOff[t] = excl;
    if (v > 0) runBase[t] = atomicAdd(&bucketCnt[t], v);
    __syncthreads();
    hist[t] = excl;  // reuse as in-block cursor
    __syncthreads();
    for (int j = t; j < nE; j += 256) {
        int d = dst[base + j], s = src[base + j];
        int idx = atomicAdd(&hist[d >> 8], 1);
        stage[idx] = ((unsigned)d << 16) | (unsigned)s;
    }
    __syncthreads();
    for (int j = t; j < nE; j += 256) {
        unsigned u = stage[j];
        int b = u >> 24;  // == dst>>8 (dst < 65536)
        int slot = runBase[b] + (j - localOff[b]);
        if (slot < CAP) bucketed[(size_t)b * CAP + slot] = u;
    }
}

// Exclusive scan of (clamped) bucket counts -> compact csr bases.
__global__ __launch_bounds__(256) void k_bucket_scan(const int* __restrict__ bucketCnt,
                                                     int* __restrict__ bucketBase, int NB) {
    __shared__ int wsum[4];
    int t = threadIdx.x;
    int v = (t < NB) ? min(bucketCnt[t], CAP) : 0;
    int excl = block_scan256(v, wsum);
    if (t < NB) bucketBase[t] = excl;
    if (t == NB - 1) bucketBase[NB] = excl + v;
}

// Per-bucket placement: node histogram -> row_ptr/dis, LDS-cursor csr staging,
// coalesced csr flush; fused xh = half(dis * x) cast for the bucket's nodes.
__global__ __launch_bounds__(256) void k_place(const unsigned int* __restrict__ bucketed,
                                               const int* __restrict__ bucketCnt,
                                               const int* __restrict__ bucketBase,
                                               const float* __restrict__ x,
                                               unsigned short* __restrict__ csr,
                                               int* __restrict__ row_ptr,
                                               float* __restrict__ dis,
                                               __half* __restrict__ xh, int N) {
    __shared__ int nodeCnt[256];
    __shared__ int wsum[4];
    __shared__ float disS[256];
    __shared__ unsigned short outS[CAP];
    int b = blockIdx.x, t = threadIdx.x;
    const unsigned int* bk = bucketed + (size_t)b * CAP;
    int cnt = min(bucketCnt[b], CAP);
    int base = bucketBase[b];
    nodeCnt[t] = 0;
    __syncthreads();
    for (int j = t; j < cnt; j += 256) atomicAdd(&nodeCnt[(bk[j] >> 16) & 255], 1);
    __syncthreads();
    int v = nodeCnt[t];
    int excl = block_scan256(v, wsum);
    int node = b * 256 + t;
    float d = rsqrtf(1.0f + (float)v);
    disS[t] = d;
    if (node < N) {
        row_ptr[node] = base + excl;
        dis[node] = d;
        if (node == N - 1) row_ptr[N] = base + excl + v;
    }
    __syncthreads();
    nodeCnt[t] = excl;  // reuse as cursor
    __syncthreads();
    for (int j = t; j < cnt; j += 256) {
        unsigned u = bk[j];
        int p = atomicAdd(&nodeCnt[(u >> 16) & 255], 1);
        outS[p] = (unsigned short)(u & 0xFFFF);
    }
    __syncthreads();
    for (int j = t; j < cnt; j += 256) csr[base + j] = outS[j];
    // fused cast: xh[node][:] = half(dis[node] * x[node][:]) for this bucket
    int nodes = min(256, N - b * 256);
    if (nodes > 0) {
        const float2* xp = (const float2*)(x + (size_t)b * 256 * 64);
        __half2* xhp = (__half2*)(xh + (size_t)b * 256 * 64);
        int total = nodes * 32;  // float2 units, 32 per node
        for (int i = t; i < total; i += 256) {
            float dd = disS[i >> 5];
            float2 vv = xp[i];
            xhp[i] = __floats2half2_rn(dd * vv.x, dd * vv.y);
        }
    }
}

// Wave-per-node gather over a 64-col fp16 dis-prescaled table:
//   a = gt[node,lane] + sum_src gt[src,lane];  r = dis_node * a (+bias, relu)
template <bool RELU, typename OutT>
__global__ __launch_bounds__(256) void k_gather64(const __half* __restrict__ gt,
                                                  const int* __restrict__ row_ptr,
                                                  const unsigned short* __restrict__ csr,
                                                  const float* __restrict__ dis,
                                                  const float* __restrict__ bias,
                                                  OutT* __restrict__ out, int n) {
    int wave = threadIdx.x >> 6, lane = threadIdx.x & 63;
    int node = blockIdx.x * 4 + wave;
    if (node >= n) return;
    int beg = row_ptr[node], end = row_ptr[node + 1];
    float a = __half2float(gt[(size_t)node * 64 + lane]);
    for (int base = beg; base < end; base += 64) {
        int m = end - base; if (m > 64) m = 64;
        int idx = csr[base + (lane < m ? lane : 0)];
        int j = 0;
        for (; j + 16 <= m; j += 16) {
            int s0 = __shfl(idx, j + 0),  s1 = __shfl(idx, j + 1);
            int s2 = __shfl(idx, j + 2),  s3 = __shfl(idx, j + 3);
            int s4 = __shfl(idx, j + 4),  s5 = __shfl(idx, j + 5);
            int s6 = __shfl(idx, j + 6),  s7 = __shfl(idx, j + 7);
            int s8 = __shfl(idx, j + 8),  s9 = __shfl(idx, j + 9);
            int sa = __shfl(idx, j + 10), sb = __shfl(idx, j + 11);
            int sc = __shfl(idx, j + 12), sd = __shfl(idx, j + 13);
            int se = __shfl(idx, j + 14), sf = __shfl(idx, j + 15);
            __half v0 = gt[(size_t)s0 * 64 + lane], v1 = gt[(size_t)s1 * 64 + lane];
            __half v2 = gt[(size_t)s2 * 64 + lane], v3 = gt[(size_t)s3 * 64 + lane];
            __half v4 = gt[(size_t)s4 * 64 + lane], v5 = gt[(size_t)s5 * 64 + lane];
            __half v6 = gt[(size_t)s6 * 64 + lane], v7 = gt[(size_t)s7 * 64 + lane];
            __half v8 = gt[(size_t)s8 * 64 + lane], v9 = gt[(size_t)s9 * 64 + lane];
            __half va = gt[(size_t)sa * 64 + lane], vb = gt[(size_t)sb * 64 + lane];
            __half vc = gt[(size_t)sc * 64 + lane], vd = gt[(size_t)sd * 64 + lane];
            __half ve = gt[(size_t)se * 64 + lane], vf = gt[(size_t)sf * 64 + lane];
            float f0 = (__half2float(v0) + __half2float(v1)) + (__half2float(v2) + __half2float(v3));
            float f1 = (__half2float(v4) + __half2float(v5)) + (__half2float(v6) + __half2float(v7));
            float f2 = (__half2float(v8) + __half2float(v9)) + (__half2float(va) + __half2float(vb));
            float f3 = (__half2float(vc) + __half2float(vd)) + (__half2float(ve) + __half2float(vf));
            a += (f0 + f1) + (f2 + f3);
        }
        for (; j + 4 <= m; j += 4) {
            int s0 = __shfl(idx, j + 0), s1 = __shfl(idx, j + 1);
            int s2 = __shfl(idx, j + 2), s3 = __shfl(idx, j + 3);
            __half v0 = gt[(size_t)s0 * 64 + lane], v1 = gt[(size_t)s1 * 64 + lane];
            __half v2 = gt[(size_t)s2 * 64 + lane], v3 = gt[(size_t)s3 * 64 + lane];
            a += (__half2float(v0) + __half2float(v1)) + (__half2float(v2) + __half2float(v3));
        }
        for (; j < m; ++j) {
            int s = __shfl(idx, j);
            a += __half2float(gt[(size_t)s * 64 + lane]);
        }
    }
    float r = dis[node] * a;
    if constexpr (RELU) r = fmaxf(r + bias[lane], 0.0f);
    if constexpr (sizeof(OutT) == 2) out[(size_t)node * 64 + lane] = __float2half(r);
    else                             out[(size_t)node * 64 + lane] = r;
}

// Fused double-GEMM: g2 = half(dis * (relu(agg1 @ W1 + b1) @ W2))
// 64 nodes/block; y1 tile lives in LDS (never touches global). 114 KB LDS.
__global__ __launch_bounds__(256) void k_gemm_fused(const __half* __restrict__ agg1,
                                                    const float* __restrict__ W1,
                                                    const float* __restrict__ b1,
                                                    const float* __restrict__ W2,
                                                    const float* __restrict__ dis,
                                                    __half* __restrict__ g2, int n) {
    __shared__ float xs[64][68];
    __shared__ float Ws1[64 * 128];
    __shared__ float ys[64][132];
    __shared__ float Ws2[128 * 64];
    int t = threadIdx.x;
    int node0 = blockIdx.x * 64;
    for (int i = t; i < 64 * 128; i += 256) Ws1[i] = W1[i];
    for (int i = t; i < 128 * 64; i += 256) Ws2[i] = W2[i];
    for (int i = t; i < 64 * 32; i += 256) {  // half2 units
        int r = i >> 5, k2 = i & 31;
        int node = node0 + r;
        float2 v = (node < n) ? __half22float2(*(const __half2*)(agg1 + (size_t)node * 64 + k2 * 2))
                              : make_float2(0.0f, 0.0f);
        xs[r][k2 * 2] = v.x;
        xs[r][k2 * 2 + 1] = v.y;
    }
    __syncthreads();
    // stage 1: ys = relu(xs @ W1 + b1); thread = 4 nodes x 8 cols
    {
        int tc = t & 15, tn = t >> 4;
        int c0 = tc * 8, nb = tn * 4;
        float acc[4][8] = {};
        #pragma unroll 4
        for (int k = 0; k < 64; ++k) {
            float x0 = xs[nb + 0][k], x1 = xs[nb + 1][k];
            float x2 = xs[nb + 2][k], x3 = xs[nb + 3][k];
            #pragma unroll
            for (int c = 0; c < 8; ++c) {
                float w = Ws1[k * 128 + c0 + c];
                acc[0][c] += x0 * w; acc[1][c] += x1 * w;
                acc[2][c] += x2 * w; acc[3][c] += x3 * w;
            }
        }
        #pragma unroll
        for (int i = 0; i < 4; ++i)
            #pragma unroll
            for (int c = 0; c < 8; ++c)
                ys[nb + i][c0 + c] = fmaxf(acc[i][c] + b1[c0 + c], 0.0f);
    }
    __syncthreads();
    // stage 2: g2 = half(dis * (ys @ W2)); thread = 4 nodes x 4 cols
    {
        int tc = t & 15, tn = t >> 4;
        int c0 = tc * 4, nb = tn * 4;
        float acc[4][4] = {};
        #pragma unroll 4
        for (int k = 0; k < 128; ++k) {
            float y0 = ys[nb + 0][k], y1 = ys[nb + 1][k];
            float y2 = ys[nb + 2][k], y3 = ys[nb + 3][k];
            #pragma unroll
            for (int c = 0; c < 4; ++c) {
                float w = Ws2[k * 64 + c0 + c];
                acc[0][c] += y0 * w; acc[1][c] += y1 * w;
                acc[2][c] += y2 * w; acc[3][c] += y3 * w;
            }
        }
        #pragma unroll
        for (int i = 0; i < 4; ++i) {
            int node = node0 + nb + i;
            if (node < n) {
                float dd = dis[node];
                #pragma unroll
                for (int c = 0; c < 4; c += 2) {
                    __half2 hv = __floats2half2_rn(dd * acc[i][c], dd * acc[i][c + 1]);
                    *(__half2*)(g2 + (size_t)node * 64 + c0 + c) = hv;
                }
            }
        }
    }
}

static inline size_t align_up(size_t v, size_t a) { return (v + a - 1) / a * a; }

extern "C" void kernel_launch(void* const* d_in, const int* in_sizes, int n_in,
                              void* d_out, int out_size, void* d_ws, size_t ws_size,
                              hipStream_t stream) {
    const float* x  = (const float*)d_in[0];
    const int*   ei = (const int*)d_in[1];
    const float* W1 = (const float*)d_in[2];
    const float* b1 = (const float*)d_in[3];
    const float* W2 = (const float*)d_in[4];
    const float* b2 = (const float*)d_in[5];
    float* out = (float*)d_out;

    const int N = in_sizes[0] / 64;   // 50000
    const int E = in_sizes[1] / 2;    // 1600000
    const int* src = ei;
    const int* dst = ei + E;
    const int NB = (N + 255) >> 8;    // 196 coarse buckets

    char* ws = (char*)d_ws;
    size_t off = 0;
    int* bucketCnt = (int*)(ws + off);      off = align_up(off + (size_t)NB * 4, 256);
    int* bucketBase = (int*)(ws + off);     off = align_up(off + (size_t)(NB + 1) * 4, 256);
    unsigned int* bucketed = (unsigned int*)(ws + off); off = align_up(off + (size_t)NB * CAP * 4, 256);
    unsigned short* csr = (unsigned short*)(ws + off);  off = align_up(off + (size_t)E * 2, 256);
    int* row_ptr = (int*)(ws + off);        off = align_up(off + (size_t)(N + 1) * 4, 256);
    float* dis = (float*)(ws + off);        off = align_up(off + (size_t)N * 4, 256);
    __half* xh = (__half*)(ws + off);       off = align_up(off + (size_t)N * 64 * 2, 256);
    __half* agg1 = (__half*)(ws + off);     off = align_up(off + (size_t)N * 64 * 2, 256);
    __half* g2 = (__half*)(ws + off);       off = align_up(off + (size_t)N * 64 * 2, 256);
    (void)ws_size;

    // CSR build (4 dispatches incl. tiny memset)
    hipMemsetAsync(bucketCnt, 0, (size_t)NB * 4, stream);
    k_partition<<<(E + EPB - 1) / EPB, THREADS, 0, stream>>>(src, dst, bucketCnt, bucketed, E);
    k_bucket_scan<<<1, THREADS, 0, stream>>>(bucketCnt, bucketBase, NB);
    k_place<<<NB, THREADS, 0, stream>>>(bucketed, bucketCnt, bucketBase, x, csr, row_ptr, dis, xh, N);

    // layer 1 aggregate + fused MLP + layer 2 aggregate
    k_gather64<false, __half><<<(N + 3) / 4, THREADS, 0, stream>>>(xh, row_ptr, csr, dis, b1, agg1, N);
    k_gemm_fused<<<(N + 63) / 64, THREADS, 0, stream>>>(agg1, W1, b1, W2, dis, g2, N);
    k_gather64<true, float><<<(N + 3) / 4, THREADS, 0, stream>>>(g2, row_ptr, csr, dis, b2, out, N);
}

// Round 8
// 165.452 us; speedup vs baseline: 1.3693x; 1.0545x over previous
//
#include <hip/hip_runtime.h>
#include <hip/hip_fp16.h>

// GCN 2-layer, aggregate-first L1 / aggregate-last L2:
//   agg1 = Â x   (gather over xh = half(dis*x), 64-col, produced in k_place)
//   y1   = half(relu(agg1 @ W1 + b1))          (GEMM1, fp16 out)
//   g2   = half(dis * (y1 @ W2))               (GEMM2, fp16 out)
//   out  = relu(dis * (g2_i + sum g2_src) + b2)  (gather)
// CSR build: direct fixed-capacity bucket partition + per-bucket placement
// fused with the xh cast. N < 65536 (u16 csr indices).

#define THREADS 256
#define EPB 4096    // edges per partition block (16 KB LDS stage)
#define CAP 16384   // per-bucket capacity (mean 8163, ~90 sigma headroom)

__device__ inline int block_scan256(int v, int* wsum) {
    int lane = threadIdx.x & 63, w = threadIdx.x >> 6;
    int x = v;
    #pragma unroll
    for (int off = 1; off < 64; off <<= 1) {
        int y = __shfl_up(x, off);
        if (lane >= off) x += y;
    }
    if (lane == 63) wsum[w] = x;
    __syncthreads();
    int woff = 0;
    #pragma unroll
    for (int i = 0; i < 4; ++i) if (i < w) woff += wsum[i];
    return woff + x - v;
}

__global__ __launch_bounds__(256) void k_partition(const int* __restrict__ src,
                                                   const int* __restrict__ dst,
                                                   int* __restrict__ bucketCnt,
                                                   unsigned int* __restrict__ bucketed, int E) {
    __shared__ int hist[256];
    __shared__ int localOff[256];
    __shared__ int runBase[256];
    __shared__ int wsum[4];
    __shared__ unsigned int stage[EPB];
    int t = threadIdx.x;
    int base = blockIdx.x * EPB;
    int nE = min(EPB, E - base);
    hist[t] = 0;
    __syncthreads();
    for (int j = t; j < nE; j += 256) atomicAdd(&hist[dst[base + j] >> 8], 1);
    __syncthreads();
    int v = hist[t];
    int excl = block_scan256(v, wsum);
    localOff[t] = excl;
    if (v > 0) runBase[t] = atomicAdd(&bucketCnt[t], v);
    __syncthreads();
    hist[t] = excl;  // reuse as in-block cursor
    __syncthreads();
    for (int j = t; j < nE; j += 256) {
        int d = dst[base + j], s = src[base + j];
        int idx = atomicAdd(&hist[d >> 8], 1);
        stage[idx] = ((unsigned)d << 16) | (unsigned)s;
    }
    __syncthreads();
    for (int j = t; j < nE; j += 256) {
        unsigned u = stage[j];
        int b = u >> 24;  // == dst>>8 (dst < 65536)
        int slot = runBase[b] + (j - localOff[b]);
        if (slot < CAP) bucketed[(size_t)b * CAP + slot] = u;
    }
}

__global__ __launch_bounds__(256) void k_bucket_scan(const int* __restrict__ bucketCnt,
                                                     int* __restrict__ bucketBase, int NB) {
    __shared__ int wsum[4];
    int t = threadIdx.x;
    int v = (t < NB) ? min(bucketCnt[t], CAP) : 0;
    int excl = block_scan256(v, wsum);
    if (t < NB) bucketBase[t] = excl;
    if (t == NB - 1) bucketBase[NB] = excl + v;
}

__global__ __launch_bounds__(256) void k_place(const unsigned int* __restrict__ bucketed,
                                               const int* __restrict__ bucketCnt,
                                               const int* __restrict__ bucketBase,
                                               const float* __restrict__ x,
                                               unsigned short* __restrict__ csr,
                                               int* __restrict__ row_ptr,
                                               float* __restrict__ dis,
                                               __half* __restrict__ xh, int N) {
    __shared__ int nodeCnt[256];
    __shared__ int wsum[4];
    __shared__ float disS[256];
    __shared__ unsigned short outS[CAP];
    int b = blockIdx.x, t = threadIdx.x;
    const unsigned int* bk = bucketed + (size_t)b * CAP;
    int cnt = min(bucketCnt[b], CAP);
    int base = bucketBase[b];
    nodeCnt[t] = 0;
    __syncthreads();
    for (int j = t; j < cnt; j += 256) atomicAdd(&nodeCnt[(bk[j] >> 16) & 255], 1);
    __syncthreads();
    int v = nodeCnt[t];
    int excl = block_scan256(v, wsum);
    int node = b * 256 + t;
    float d = rsqrtf(1.0f + (float)v);
    disS[t] = d;
    if (node < N) {
        row_ptr[node] = base + excl;
        dis[node] = d;
        if (node == N - 1) row_ptr[N] = base + excl + v;
    }
    __syncthreads();
    nodeCnt[t] = excl;  // reuse as cursor
    __syncthreads();
    for (int j = t; j < cnt; j += 256) {
        unsigned u = bk[j];
        int p = atomicAdd(&nodeCnt[(u >> 16) & 255], 1);
        outS[p] = (unsigned short)(u & 0xFFFF);
    }
    __syncthreads();
    for (int j = t; j < cnt; j += 256) csr[base + j] = outS[j];
    // fused cast: xh[node][:] = half(dis[node] * x[node][:]) for this bucket
    int nodes = min(256, N - b * 256);
    if (nodes > 0) {
        const float2* xp = (const float2*)(x + (size_t)b * 256 * 64);
        __half2* xhp = (__half2*)(xh + (size_t)b * 256 * 64);
        int total = nodes * 32;  // float2 units, 32 per node
        for (int i = t; i < total; i += 256) {
            float dd = disS[i >> 5];
            float2 vv = xp[i];
            xhp[i] = __floats2half2_rn(dd * vv.x, dd * vv.y);
        }
    }
}

// Wave-per-node gather over a 64-col fp16 dis-prescaled table.
template <bool RELU, typename OutT>
__global__ __launch_bounds__(256) void k_gather64(const __half* __restrict__ gt,
                                                  const int* __restrict__ row_ptr,
                                                  const unsigned short* __restrict__ csr,
                                                  const float* __restrict__ dis,
                                                  const float* __restrict__ bias,
                                                  OutT* __restrict__ out, int n) {
    int wave = threadIdx.x >> 6, lane = threadIdx.x & 63;
    int node = blockIdx.x * 4 + wave;
    if (node >= n) return;
    int beg = row_ptr[node], end = row_ptr[node + 1];
    float a = __half2float(gt[(size_t)node * 64 + lane]);
    for (int base = beg; base < end; base += 64) {
        int m = end - base; if (m > 64) m = 64;
        int idx = csr[base + (lane < m ? lane : 0)];
        int j = 0;
        for (; j + 16 <= m; j += 16) {
            int s0 = __shfl(idx, j + 0),  s1 = __shfl(idx, j + 1);
            int s2 = __shfl(idx, j + 2),  s3 = __shfl(idx, j + 3);
            int s4 = __shfl(idx, j + 4),  s5 = __shfl(idx, j + 5);
            int s6 = __shfl(idx, j + 6),  s7 = __shfl(idx, j + 7);
            int s8 = __shfl(idx, j + 8),  s9 = __shfl(idx, j + 9);
            int sa = __shfl(idx, j + 10), sb = __shfl(idx, j + 11);
            int sc = __shfl(idx, j + 12), sd = __shfl(idx, j + 13);
            int se = __shfl(idx, j + 14), sf = __shfl(idx, j + 15);
            __half v0 = gt[(size_t)s0 * 64 + lane], v1 = gt[(size_t)s1 * 64 + lane];
            __half v2 = gt[(size_t)s2 * 64 + lane], v3 = gt[(size_t)s3 * 64 + lane];
            __half v4 = gt[(size_t)s4 * 64 + lane], v5 = gt[(size_t)s5 * 64 + lane];
            __half v6 = gt[(size_t)s6 * 64 + lane], v7 = gt[(size_t)s7 * 64 + lane];
            __half v8 = gt[(size_t)s8 * 64 + lane], v9 = gt[(size_t)s9 * 64 + lane];
            __half va = gt[(size_t)sa * 64 + lane], vb = gt[(size_t)sb * 64 + lane];
            __half vc = gt[(size_t)sc * 64 + lane], vd = gt[(size_t)sd * 64 + lane];
            __half ve = gt[(size_t)se * 64 + lane], vf = gt[(size_t)sf * 64 + lane];
            float f0 = (__half2float(v0) + __half2float(v1)) + (__half2float(v2) + __half2float(v3));
            float f1 = (__half2float(v4) + __half2float(v5)) + (__half2float(v6) + __half2float(v7));
            float f2 = (__half2float(v8) + __half2float(v9)) + (__half2float(va) + __half2float(vb));
            float f3 = (__half2float(vc) + __half2float(vd)) + (__half2float(ve) + __half2float(vf));
            a += (f0 + f1) + (f2 + f3);
        }
        for (; j + 4 <= m; j += 4) {
            int s0 = __shfl(idx, j + 0), s1 = __shfl(idx, j + 1);
            int s2 = __shfl(idx, j + 2), s3 = __shfl(idx, j + 3);
            __half v0 = gt[(size_t)s0 * 64 + lane], v1 = gt[(size_t)s1 * 64 + lane];
            __half v2 = gt[(size_t)s2 * 64 + lane], v3 = gt[(size_t)s3 * 64 + lane];
            a += (__half2float(v0) + __half2float(v1)) + (__half2float(v2) + __half2float(v3));
        }
        for (; j < m; ++j) {
            int s = __shfl(idx, j);
            a += __half2float(gt[(size_t)s * 64 + lane]);
        }
    }
    float r = dis[node] * a;
    if constexpr (RELU) r = fmaxf(r + bias[lane], 0.0f);
    if constexpr (sizeof(OutT) == 2) out[(size_t)node * 64 + lane] = __float2half(r);
    else                             out[(size_t)node * 64 + lane] = r;
}

// Register-blocked GEMM, fp16 in / fp16 out. 64 nodes/block, thread = 4 nodes
// x CPT cols. MODE 0: out = half(relu(acc+bias)); MODE 1: out = half(dis*acc).
template <int IN, int OUT, int CPT, int MODE>
__global__ __launch_bounds__(256) void k_gemm(const __half* __restrict__ xin,
                                              const float* __restrict__ W,
                                              const float* __restrict__ dis,
                                              const float* __restrict__ bias,
                                              __half* __restrict__ outh, int n) {
    constexpr int BN = 64;
    constexpr int XPAD = IN + 4;
    __shared__ float xs[BN * XPAD];
    __shared__ float Ws[IN * OUT];
    int t = threadIdx.x;
    for (int i = t; i < IN * OUT; i += 256) Ws[i] = W[i];
    int node0 = blockIdx.x * BN;
    for (int i = t; i < BN * (IN / 2); i += 256) {  // half2 units
        int r = i / (IN / 2), k2 = i % (IN / 2);
        int node = node0 + r;
        float2 v = (node < n) ? __half22float2(*(const __half2*)(xin + (size_t)node * IN + k2 * 2))
                              : make_float2(0.0f, 0.0f);
        xs[r * XPAD + k2 * 2] = v.x;
        xs[r * XPAD + k2 * 2 + 1] = v.y;
    }
    __syncthreads();
    constexpr int CG = OUT / CPT;
    int tc = t % CG, tn = t / CG;
    int c0 = tc * CPT, nb = tn * 4;
    float acc[4][CPT] = {};
    #pragma unroll 4
    for (int k = 0; k < IN; ++k) {
        float xv0 = xs[(nb + 0) * XPAD + k];
        float xv1 = xs[(nb + 1) * XPAD + k];
        float xv2 = xs[(nb + 2) * XPAD + k];
        float xv3 = xs[(nb + 3) * XPAD + k];
        #pragma unroll
        for (int c = 0; c < CPT; ++c) {
            float w = Ws[k * OUT + c0 + c];
            acc[0][c] += xv0 * w;
            acc[1][c] += xv1 * w;
            acc[2][c] += xv2 * w;
            acc[3][c] += xv3 * w;
        }
    }
    #pragma unroll
    for (int i = 0; i < 4; ++i) {
        int node = node0 + nb + i;
        if (node < n) {
            if constexpr (MODE == 0) {
                #pragma unroll
                for (int c = 0; c < CPT; c += 2) {
                    float r0 = fmaxf(acc[i][c] + bias[c0 + c], 0.0f);
                    float r1 = fmaxf(acc[i][c + 1] + bias[c0 + c + 1], 0.0f);
                    *(__half2*)(&outh[(size_t)node * OUT + c0 + c]) = __floats2half2_rn(r0, r1);
                }
            } else {
                float d = dis[node];
                #pragma unroll
                for (int c = 0; c < CPT; c += 2) {
                    __half2 hv = __floats2half2_rn(d * acc[i][c], d * acc[i][c + 1]);
                    *(__half2*)(&outh[(size_t)node * OUT + c0 + c]) = hv;
                }
            }
        }
    }
}

static inline size_t align_up(size_t v, size_t a) { return (v + a - 1) / a * a; }

extern "C" void kernel_launch(void* const* d_in, const int* in_sizes, int n_in,
                              void* d_out, int out_size, void* d_ws, size_t ws_size,
                              hipStream_t stream) {
    const float* x  = (const float*)d_in[0];
    const int*   ei = (const int*)d_in[1];
    const float* W1 = (const float*)d_in[2];
    const float* b1 = (const float*)d_in[3];
    const float* W2 = (const float*)d_in[4];
    const float* b2 = (const float*)d_in[5];
    float* out = (float*)d_out;

    const int N = in_sizes[0] / 64;   // 50000
    const int E = in_sizes[1] / 2;    // 1600000
    const int* src = ei;
    const int* dst = ei + E;
    const int NB = (N + 255) >> 8;    // 196 coarse buckets

    char* ws = (char*)d_ws;
    size_t off = 0;
    int* bucketCnt = (int*)(ws + off);      off = align_up(off + (size_t)NB * 4, 256);
    int* bucketBase = (int*)(ws + off);     off = align_up(off + (size_t)(NB + 1) * 4, 256);
    unsigned int* bucketed = (unsigned int*)(ws + off); off = align_up(off + (size_t)NB * CAP * 4, 256);
    unsigned short* csr = (unsigned short*)(ws + off);  off = align_up(off + (size_t)E * 2, 256);
    int* row_ptr = (int*)(ws + off);        off = align_up(off + (size_t)(N + 1) * 4, 256);
    float* dis = (float*)(ws + off);        off = align_up(off + (size_t)N * 4, 256);
    __half* xh = (__half*)(ws + off);       off = align_up(off + (size_t)N * 64 * 2, 256);
    __half* agg1 = (__half*)(ws + off);     off = align_up(off + (size_t)N * 64 * 2, 256);
    __half* y1 = (__half*)(ws + off);       off = align_up(off + (size_t)N * 128 * 2, 256);
    __half* g2 = (__half*)(ws + off);       off = align_up(off + (size_t)N * 64 * 2, 256);
    (void)ws_size;

    // CSR build
    hipMemsetAsync(bucketCnt, 0, (size_t)NB * 4, stream);
    k_partition<<<(E + EPB - 1) / EPB, THREADS, 0, stream>>>(src, dst, bucketCnt, bucketed, E);
    k_bucket_scan<<<1, THREADS, 0, stream>>>(bucketCnt, bucketBase, NB);
    k_place<<<NB, THREADS, 0, stream>>>(bucketed, bucketCnt, bucketBase, x, csr, row_ptr, dis, xh, N);

    // layer 1 aggregate -> MLP (split GEMMs, fp16 y1) -> layer 2 aggregate
    k_gather64<false, __half><<<(N + 3) / 4, THREADS, 0, stream>>>(xh, row_ptr, csr, dis, b1, agg1, N);
    k_gemm<64, 128, 8, 0><<<(N + 63) / 64, THREADS, 0, stream>>>(agg1, W1, nullptr, b1, y1, N);
    k_gemm<128, 64, 4, 1><<<(N + 63) / 64, THREADS, 0, stream>>>(y1, W2, dis, nullptr, g2, N);
    k_gather64<true, float><<<(N + 3) / 4, THREADS, 0, stream>>>(g2, row_ptr, csr, dis, b2, out, N);
}

// Round 9
// 158.404 us; speedup vs baseline: 1.4303x; 1.0445x over previous
//
#include <hip/hip_runtime.h>
#include <hip/hip_fp16.h>

// GCN 2-layer, aggregate-first L1 / aggregate-last L2:
//   agg1 = Â x   (gather over xh = half(dis*x), 64-col, produced in k_place)
//   y1   = half(relu(agg1 @ W1 + b1))          (GEMM1, fp16 out)
//   g2   = half(dis * (y1 @ W2))               (GEMM2, fp16 out)
//   out  = relu(dis * (g2_i + sum g2_src) + b2)  (gather)
// Gather: 2 nodes per wave (half2 per lane) — one vector load serves 2 edges.
// CSR build: fixed-capacity bucket partition; bucket scan folded into k_place.
// N < 65536 (u16 csr indices).

#define THREADS 256
#define EPB 4096    // edges per partition block (16 KB LDS stage)
#define CAP 16384   // per-bucket capacity (mean 8163, ~90 sigma headroom)

__device__ inline int block_scan256(int v, int* wsum) {
    int lane = threadIdx.x & 63, w = threadIdx.x >> 6;
    int x = v;
    #pragma unroll
    for (int off = 1; off < 64; off <<= 1) {
        int y = __shfl_up(x, off);
        if (lane >= off) x += y;
    }
    if (lane == 63) wsum[w] = x;
    __syncthreads();
    int woff = 0;
    #pragma unroll
    for (int i = 0; i < 4; ++i) if (i < w) woff += wsum[i];
    return woff + x - v;
}

__global__ __launch_bounds__(256) void k_partition(const int* __restrict__ src,
                                                   const int* __restrict__ dst,
                                                   int* __restrict__ bucketCnt,
                                                   unsigned int* __restrict__ bucketed, int E) {
    __shared__ int hist[256];
    __shared__ int localOff[256];
    __shared__ int runBase[256];
    __shared__ int wsum[4];
    __shared__ unsigned int stage[EPB];
    int t = threadIdx.x;
    int base = blockIdx.x * EPB;
    int nE = min(EPB, E - base);
    hist[t] = 0;
    __syncthreads();
    for (int j = t; j < nE; j += 256) atomicAdd(&hist[dst[base + j] >> 8], 1);
    __syncthreads();
    int v = hist[t];
    int excl = block_scan256(v, wsum);
    localOff[t] = excl;
    if (v > 0) runBase[t] = atomicAdd(&bucketCnt[t], v);
    __syncthreads();
    hist[t] = excl;  // reuse as in-block cursor
    __syncthreads();
    for (int j = t; j < nE; j += 256) {
        int d = dst[base + j], s = src[base + j];
        int idx = atomicAdd(&hist[d >> 8], 1);
        stage[idx] = ((unsigned)d << 16) | (unsigned)s;
    }
    __syncthreads();
    for (int j = t; j < nE; j += 256) {
        unsigned u = stage[j];
        int b = u >> 24;  // == dst>>8 (dst < 65536)
        int slot = runBase[b] + (j - localOff[b]);
        if (slot < CAP) bucketed[(size_t)b * CAP + slot] = u;
    }
}

// Per-bucket placement. The 196-entry bucket scan is recomputed in-block
// (cheap) instead of a separate dispatch. Fused xh = half(dis*x) cast.
__global__ __launch_bounds__(256) void k_place(const unsigned int* __restrict__ bucketed,
                                               const int* __restrict__ bucketCnt,
                                               const float* __restrict__ x,
                                               unsigned short* __restrict__ csr,
                                               int* __restrict__ row_ptr,
                                               float* __restrict__ dis,
                                               __half* __restrict__ xh, int N, int NB) {
    __shared__ int nodeCnt[256];
    __shared__ int wsum[4];
    __shared__ int baseS;
    __shared__ float disS[256];
    __shared__ unsigned short outS[CAP];
    int b = blockIdx.x, t = threadIdx.x;
    // in-block exclusive scan of bucket counts -> this bucket's csr base
    {
        int v = (t < NB) ? min(bucketCnt[t], CAP) : 0;
        int excl = block_scan256(v, wsum);
        if (t == b) baseS = excl;
        __syncthreads();
    }
    int base = baseS;
    const unsigned int* bk = bucketed + (size_t)b * CAP;
    int cnt = min(bucketCnt[b], CAP);
    nodeCnt[t] = 0;
    __syncthreads();
    for (int j = t; j < cnt; j += 256) atomicAdd(&nodeCnt[(bk[j] >> 16) & 255], 1);
    __syncthreads();
    int v = nodeCnt[t];
    int excl = block_scan256(v, wsum);
    int node = b * 256 + t;
    float d = rsqrtf(1.0f + (float)v);
    disS[t] = d;
    if (node < N) {
        row_ptr[node] = base + excl;
        dis[node] = d;
        if (node == N - 1) row_ptr[N] = base + excl + v;
    }
    __syncthreads();
    nodeCnt[t] = excl;  // reuse as cursor
    __syncthreads();
    for (int j = t; j < cnt; j += 256) {
        unsigned u = bk[j];
        int p = atomicAdd(&nodeCnt[(u >> 16) & 255], 1);
        outS[p] = (unsigned short)(u & 0xFFFF);
    }
    __syncthreads();
    for (int j = t; j < cnt; j += 256) csr[base + j] = outS[j];
    // fused cast: xh[node][:] = half(dis[node] * x[node][:]) for this bucket
    int nodes = min(256, N - b * 256);
    if (nodes > 0) {
        const float2* xp = (const float2*)(x + (size_t)b * 256 * 64);
        __half2* xhp = (__half2*)(xh + (size_t)b * 256 * 64);
        int total = nodes * 32;  // float2 units, 32 per node
        for (int i = t; i < total; i += 256) {
            float dd = disS[i >> 5];
            float2 vv = xp[i];
            xhp[i] = __floats2half2_rn(dd * vv.x, dd * vv.y);
        }
    }
}

// Gather, 2 nodes per wave: lanes 0-31 serve node A, 32-63 node B.
// Each lane accumulates a half2 (2 cols); one 64-lane load = 2 edge-rows.
template <bool RELU, typename OutT>
__global__ __launch_bounds__(256) void k_gather64(const __half* __restrict__ gt,
                                                  const int* __restrict__ row_ptr,
                                                  const unsigned short* __restrict__ csr,
                                                  const float* __restrict__ dis,
                                                  const float* __restrict__ bias,
                                                  OutT* __restrict__ out, int n) {
    int wave = threadIdx.x >> 6, lane = threadIdx.x & 63;
    int hb = lane & 32;       // half base (0 or 32) for shfl sources
    int col2 = lane & 31;     // half2 column index
    int node = blockIdx.x * 8 + wave * 2 + (lane >> 5);
    bool valid = node < n;
    int nodeC = valid ? node : (n - 1);
    int beg = row_ptr[nodeC], end = row_ptr[nodeC + 1];
    int mt = end - beg;
    const __half2* gp = (const __half2*)gt;  // row stride = 32 half2
    float2 sv = __half22float2(gp[(size_t)nodeC * 32 + col2]);
    float a0 = sv.x, a1 = sv.y;
    for (int base = 0; base < mt; base += 32) {
        int m = mt - base; if (m > 32) m = 32;
        int idx = csr[beg + base + (col2 < m ? col2 : m - 1)];
        int j = 0;
        for (; j + 8 <= m; j += 8) {
            int s0 = __shfl(idx, hb + j + 0), s1 = __shfl(idx, hb + j + 1);
            int s2 = __shfl(idx, hb + j + 2), s3 = __shfl(idx, hb + j + 3);
            int s4 = __shfl(idx, hb + j + 4), s5 = __shfl(idx, hb + j + 5);
            int s6 = __shfl(idx, hb + j + 6), s7 = __shfl(idx, hb + j + 7);
            float2 v0 = __half22float2(gp[(size_t)s0 * 32 + col2]);
            float2 v1 = __half22float2(gp[(size_t)s1 * 32 + col2]);
            float2 v2 = __half22float2(gp[(size_t)s2 * 32 + col2]);
            float2 v3 = __half22float2(gp[(size_t)s3 * 32 + col2]);
            float2 v4 = __half22float2(gp[(size_t)s4 * 32 + col2]);
            float2 v5 = __half22float2(gp[(size_t)s5 * 32 + col2]);
            float2 v6 = __half22float2(gp[(size_t)s6 * 32 + col2]);
            float2 v7 = __half22float2(gp[(size_t)s7 * 32 + col2]);
            a0 += ((v0.x + v1.x) + (v2.x + v3.x)) + ((v4.x + v5.x) + (v6.x + v7.x));
            a1 += ((v0.y + v1.y) + (v2.y + v3.y)) + ((v4.y + v5.y) + (v6.y + v7.y));
        }
        for (; j < m; ++j) {
            int s = __shfl(idx, hb + j);
            float2 v = __half22float2(gp[(size_t)s * 32 + col2]);
            a0 += v.x; a1 += v.y;
        }
    }
    if (valid) {
        float dd = dis[node];
        float r0 = dd * a0, r1 = dd * a1;
        if constexpr (RELU) {
            r0 = fmaxf(r0 + bias[col2 * 2], 0.0f);
            r1 = fmaxf(r1 + bias[col2 * 2 + 1], 0.0f);
        }
        if constexpr (sizeof(OutT) == 2) {
            *(__half2*)((__half*)out + (size_t)node * 64 + col2 * 2) = __floats2half2_rn(r0, r1);
        } else {
            *(float2*)((float*)out + (size_t)node * 64 + col2 * 2) = make_float2(r0, r1);
        }
    }
}

// Register-blocked GEMM, fp16 in / fp16 out. 64 nodes/block, thread = 4 nodes
// x CPT cols. MODE 0: out = half(relu(acc+bias)); MODE 1: out = half(dis*acc).
template <int IN, int OUT, int CPT, int MODE>
__global__ __launch_bounds__(256) void k_gemm(const __half* __restrict__ xin,
                                              const float* __restrict__ W,
                                              const float* __restrict__ dis,
                                              const float* __restrict__ bias,
                                              __half* __restrict__ outh, int n) {
    constexpr int BN = 64;
    constexpr int XPAD = IN + 4;
    __shared__ float xs[BN * XPAD];
    __shared__ float Ws[IN * OUT];
    int t = threadIdx.x;
    for (int i = t; i < IN * OUT; i += 256) Ws[i] = W[i];
    int node0 = blockIdx.x * BN;
    for (int i = t; i < BN * (IN / 2); i += 256) {  // half2 units
        int r = i / (IN / 2), k2 = i % (IN / 2);
        int node = node0 + r;
        float2 v = (node < n) ? __half22float2(*(const __half2*)(xin + (size_t)node * IN + k2 * 2))
                              : make_float2(0.0f, 0.0f);
        xs[r * XPAD + k2 * 2] = v.x;
        xs[r * XPAD + k2 * 2 + 1] = v.y;
    }
    __syncthreads();
    constexpr int CG = OUT / CPT;
    int tc = t % CG, tn = t / CG;
    int c0 = tc * CPT, nb = tn * 4;
    float acc[4][CPT] = {};
    #pragma unroll 4
    for (int k = 0; k < IN; ++k) {
        float xv0 = xs[(nb + 0) * XPAD + k];
        float xv1 = xs[(nb + 1) * XPAD + k];
        float xv2 = xs[(nb + 2) * XPAD + k];
        float xv3 = xs[(nb + 3) * XPAD + k];
        #pragma unroll
        for (int c = 0; c < CPT; ++c) {
            float w = Ws[k * OUT + c0 + c];
            acc[0][c] += xv0 * w;
            acc[1][c] += xv1 * w;
            acc[2][c] += xv2 * w;
            acc[3][c] += xv3 * w;
        }
    }
    #pragma unroll
    for (int i = 0; i < 4; ++i) {
        int node = node0 + nb + i;
        if (node < n) {
            if constexpr (MODE == 0) {
                #pragma unroll
                for (int c = 0; c < CPT; c += 2) {
                    float r0 = fmaxf(acc[i][c] + bias[c0 + c], 0.0f);
                    float r1 = fmaxf(acc[i][c + 1] + bias[c0 + c + 1], 0.0f);
                    *(__half2*)(&outh[(size_t)node * OUT + c0 + c]) = __floats2half2_rn(r0, r1);
                }
            } else {
                float d = dis[node];
                #pragma unroll
                for (int c = 0; c < CPT; c += 2) {
                    __half2 hv = __floats2half2_rn(d * acc[i][c], d * acc[i][c + 1]);
                    *(__half2*)(&outh[(size_t)node * OUT + c0 + c]) = hv;
                }
            }
        }
    }
}

static inline size_t align_up(size_t v, size_t a) { return (v + a - 1) / a * a; }

extern "C" void kernel_launch(void* const* d_in, const int* in_sizes, int n_in,
                              void* d_out, int out_size, void* d_ws, size_t ws_size,
                              hipStream_t stream) {
    const float* x  = (const float*)d_in[0];
    const int*   ei = (const int*)d_in[1];
    const float* W1 = (const float*)d_in[2];
    const float* b1 = (const float*)d_in[3];
    const float* W2 = (const float*)d_in[4];
    const float* b2 = (const float*)d_in[5];
    float* out = (float*)d_out;

    const int N = in_sizes[0] / 64;   // 50000
    const int E = in_sizes[1] / 2;    // 1600000
    const int* src = ei;
    const int* dst = ei + E;
    const int NB = (N + 255) >> 8;    // 196 coarse buckets

    char* ws = (char*)d_ws;
    size_t off = 0;
    int* bucketCnt = (int*)(ws + off);      off = align_up(off + (size_t)NB * 4, 256);
    unsigned int* bucketed = (unsigned int*)(ws + off); off = align_up(off + (size_t)NB * CAP * 4, 256);
    unsigned short* csr = (unsigned short*)(ws + off);  off = align_up(off + (size_t)E * 2, 256);
    int* row_ptr = (int*)(ws + off);        off = align_up(off + (size_t)(N + 1) * 4, 256);
    float* dis = (float*)(ws + off);        off = align_up(off + (size_t)N * 4, 256);
    __half* xh = (__half*)(ws + off);       off = align_up(off + (size_t)N * 64 * 2, 256);
    __half* agg1 = (__half*)(ws + off);     off = align_up(off + (size_t)N * 64 * 2, 256);
    __half* y1 = (__half*)(ws + off);       off = align_up(off + (size_t)N * 128 * 2, 256);
    __half* g2 = (__half*)(ws + off);       off = align_up(off + (size_t)N * 64 * 2, 256);
    (void)ws_size;

    // CSR build (3 dispatches incl. tiny memset)
    hipMemsetAsync(bucketCnt, 0, (size_t)NB * 4, stream);
    k_partition<<<(E + EPB - 1) / EPB, THREADS, 0, stream>>>(src, dst, bucketCnt, bucketed, E);
    k_place<<<NB, THREADS, 0, stream>>>(bucketed, bucketCnt, x, csr, row_ptr, dis, xh, N, NB);

    // layer 1 aggregate -> MLP (split GEMMs, fp16 y1) -> layer 2 aggregate
    k_gather64<false, __half><<<(N + 7) / 8, THREADS, 0, stream>>>(xh, row_ptr, csr, dis, b1, agg1, N);
    k_gemm<64, 128, 8, 0><<<(N + 63) / 64, THREADS, 0, stream>>>(agg1, W1, nullptr, b1, y1, N);
    k_gemm<128, 64, 4, 1><<<(N + 63) / 64, THREADS, 0, stream>>>(y1, W2, dis, nullptr, g2, N);
    k_gather64<true, float><<<(N + 7) / 8, THREADS, 0, stream>>>(g2, row_ptr, csr, dis, b2, out, N);
}